// Round 1
// baseline (348.801 us; speedup 1.0000x reference)
//
#include <hip/hip_runtime.h>

#define NN 50000
#define NE 800000
#define KF 256
#define MF 64

// hw[i][j] = (sum_k h[i][k] * W[k][j]) * norm[i]
// Block = 256 threads = 4 waves; each wave computes 4 rows x 64 cols.
// W staged in LDS [k][col] (64 KB -> 2 blocks/CU). h read as wave-uniform
// float4 (readfirstlane forces SGPR base -> s_load broadcast).
__global__ __launch_bounds__(256, 2) void gemm_norm(
    const float* __restrict__ h, const float* __restrict__ W,
    const float* __restrict__ norm, float* __restrict__ hw) {
  __shared__ float ws[KF * MF];  // 64 KB
  const int t = threadIdx.x;
  {
    const float4* W4 = (const float4*)W;
    float4* s4 = (float4*)ws;
#pragma unroll
    for (int i = 0; i < 16; ++i) s4[i * 256 + t] = W4[i * 256 + t];
  }
  __syncthreads();

  const int col = t & 63;
  const int wv = __builtin_amdgcn_readfirstlane(t >> 6);  // wave id, uniform
  const int row0 = blockIdx.x * 16 + wv * 4;
  const float4* h4 = (const float4*)(h + (size_t)row0 * KF);

  float acc0 = 0.f, acc1 = 0.f, acc2 = 0.f, acc3 = 0.f;
#pragma unroll 4
  for (int k4 = 0; k4 < KF / 4; ++k4) {
    float4 a0 = h4[k4];
    float4 a1 = h4[64 + k4];
    float4 a2 = h4[128 + k4];
    float4 a3 = h4[192 + k4];
    const float* wp = ws + k4 * 4 * MF + col;
    float w0 = wp[0], w1 = wp[MF], w2 = wp[2 * MF], w3 = wp[3 * MF];
    acc0 += a0.x * w0; acc0 += a0.y * w1; acc0 += a0.z * w2; acc0 += a0.w * w3;
    acc1 += a1.x * w0; acc1 += a1.y * w1; acc1 += a1.z * w2; acc1 += a1.w * w3;
    acc2 += a2.x * w0; acc2 += a2.y * w1; acc2 += a2.z * w2; acc2 += a2.w * w3;
    acc3 += a3.x * w0; acc3 += a3.y * w1; acc3 += a3.z * w2; acc3 += a3.w * w3;
  }
  const float n0 = norm[row0 + 0], n1 = norm[row0 + 1];
  const float n2 = norm[row0 + 2], n3 = norm[row0 + 3];
  hw[(size_t)(row0 + 0) * MF + col] = acc0 * n0;
  hw[(size_t)(row0 + 1) * MF + col] = acc1 * n1;
  hw[(size_t)(row0 + 2) * MF + col] = acc2 * n2;
  hw[(size_t)(row0 + 3) * MF + col] = acc3 * n3;
}

// One wave per edge, lane = feature. agg[dst] += hw[src].
__global__ __launch_bounds__(256) void scatter_edges(
    const int* __restrict__ src, const int* __restrict__ dst,
    const float* __restrict__ hw, float* __restrict__ agg) {
  const int tid = blockIdx.x * 256 + threadIdx.x;
  const int e = tid >> 6;
  const int lane = tid & 63;
  if (e < NE) {
    const int s = src[e];
    const int d = dst[e];
    atomicAdd(&agg[(size_t)d * MF + lane], hw[(size_t)s * MF + lane]);
  }
}

// out = relu(agg * norm + bias), float4-vectorized.
__global__ __launch_bounds__(256) void finalize(
    const float* __restrict__ agg, const float* __restrict__ norm,
    const float* __restrict__ bias, float* __restrict__ out) {
  const int tid = blockIdx.x * 256 + threadIdx.x;  // float4 index
  const int node = tid >> 4;                       // 16 float4 per node
  const int f4 = tid & 15;
  float4 a = ((const float4*)agg)[tid];
  float4 b = ((const float4*)bias)[f4];
  const float n = norm[node];
  float4 o;
  o.x = fmaxf(a.x * n + b.x, 0.f);
  o.y = fmaxf(a.y * n + b.y, 0.f);
  o.z = fmaxf(a.z * n + b.z, 0.f);
  o.w = fmaxf(a.w * n + b.w, 0.f);
  ((float4*)out)[tid] = o;
}

extern "C" void kernel_launch(void* const* d_in, const int* in_sizes, int n_in,
                              void* d_out, int out_size, void* d_ws, size_t ws_size,
                              hipStream_t stream) {
  const float* h = (const float*)d_in[0];
  const float* norm = (const float*)d_in[1];
  const float* W = (const float*)d_in[2];
  const float* bias = (const float*)d_in[3];
  const int* src = (const int*)d_in[4];
  const int* dst = (const int*)d_in[5];
  float* out = (float*)d_out;

  float* hw = (float*)d_ws;                     // NN*MF floats = 12.8 MB
  float* agg = hw + (size_t)NN * MF;            // NN*MF floats = 12.8 MB
  if (ws_size < 2ull * NN * MF * sizeof(float)) return;  // fail loudly

  hipMemsetAsync(agg, 0, (size_t)NN * MF * sizeof(float), stream);

  gemm_norm<<<NN / 16, 256, 0, stream>>>(h, W, norm, hw);        // 3125 blocks
  scatter_edges<<<(NE * 64) / 256, 256, 0, stream>>>(src, dst, hw, agg);
  finalize<<<(NN * MF / 4) / 256, 256, 0, stream>>>(agg, norm, bias, out);
}